// Round 8
// baseline (198.600 us; speedup 1.0000x reference)
//
#include <hip/hip_runtime.h>
#include <hip/hip_bf16.h>

// ReparamEmbeddings: V_ORIG=32000, V_NEW=8000, D=1024, R=16, N=16384
// indices: int32 [N], index_map: int32 [V_NEW]
// emb_weight: f32 [V_ORIG, D], down: f32 [V_NEW, D, R], up: f32 [V_NEW, R, D]
// out: f32 [N, 1, D]
//
// Dedup via linked list (head[v]/next[n]). One wave per vocab entry v,
// V-ORDERED (v = 4*blockIdx + wave-in-block) so concurrently-resident waves
// stream ADJACENT 64KB regions of down/up -> aggregate near-sequential HBM
// sweep (DRAM row-buffer friendly), unlike the random-ordered worklist of the
// previous round. Factor streams + output writes are nontemporal (zero reuse).
// The 4KB e row is staged in LDS so phase 1 is a single sequential stream.

#define DDIM 1024
#define RDIM 16

typedef float v4f __attribute__((ext_vector_type(4)));

static __device__ __forceinline__ v4f ldnt(const float* p) {
    return __builtin_nontemporal_load((const v4f*)p);
}
static __device__ __forceinline__ void stnt(float* p, v4f v) {
    __builtin_nontemporal_store(v, (v4f*)p);
}
static __device__ __forceinline__ v4f sel4(bool c, v4f a, v4f b) {
    v4f r;
    r[0] = c ? a[0] : b[0];
    r[1] = c ? a[1] : b[1];
    r[2] = c ? a[2] : b[2];
    r[3] = c ? a[3] : b[3];
    return r;
}

__global__ __launch_bounds__(256) void init_head_kernel(int* __restrict__ head, int V) {
    int v = blockIdx.x * 256 + threadIdx.x;
    if (v < V) head[v] = -1;
}

__global__ __launch_bounds__(256) void link_kernel(const int* __restrict__ idx,
                                                   int* __restrict__ head,
                                                   int* __restrict__ next, int n) {
    int i = blockIdx.x * 256 + threadIdx.x;
    if (i < n) next[i] = atomicExch(&head[idx[i]], i);
}

// Compute the output row for vocab entry v into a0..a3.
// Phase 1: c0=lane&3 owns r-quad [4c0,4c0+4); dgrp=lane>>2; d = dgrp+16k.
//   down byte addr = lane*16 + k*1024 -> contiguous 1KB per wave instr.
// Butterfly masks 4..32 reduce each lane-class; 12-shuffle ladder
// redistributes all 16 h values to every lane.
// Phase 2: lane owns d = q*256 + lane*4; up rows wave-uniform, coalesced.
static __device__ __forceinline__ void compute_row(
    const float* __restrict__ e_lds,
    const float* __restrict__ dn,
    const float* __restrict__ u,
    int lane, v4f& a0, v4f& a1, v4f& a2, v4f& a3)
{
    const int c0   = lane & 3;
    const int dgrp = lane >> 2;

    // ---- Phase 1: sequential NT stream of down[v] ----
    v4f hp = {0.f, 0.f, 0.f, 0.f};
    const float* dnb = dn + (dgrp << 4) + (c0 << 2);
    #pragma unroll 8
    for (int k = 0; k < 64; ++k) {
        const float ed = e_lds[(k << 4) + dgrp];      // broadcast ds_read
        const v4f dq = ldnt(dnb + (k << 8));
        hp += ed * dq;
    }

    // ---- Reduce within each class (lanes 4 apart) ----
    #pragma unroll
    for (int m = 4; m < 64; m <<= 1) {
        v4f t;
        t[0] = __shfl_xor(hp[0], m, 64);
        t[1] = __shfl_xor(hp[1], m, 64);
        t[2] = __shfl_xor(hp[2], m, 64);
        t[3] = __shfl_xor(hp[3], m, 64);
        hp += t;
    }

    // ---- Redistribute all four class-quads to every lane ----
    v4f t1;
    t1[0] = __shfl_xor(hp[0], 1, 64);
    t1[1] = __shfl_xor(hp[1], 1, 64);
    t1[2] = __shfl_xor(hp[2], 1, 64);
    t1[3] = __shfl_xor(hp[3], 1, 64);
    const bool odd = (c0 & 1) != 0;
    v4f pe = sel4(odd, t1, hp);
    v4f po = sel4(odd, hp, t1);
    v4f pe2, po2;
    pe2[0] = __shfl_xor(pe[0], 2, 64);
    pe2[1] = __shfl_xor(pe[1], 2, 64);
    pe2[2] = __shfl_xor(pe[2], 2, 64);
    pe2[3] = __shfl_xor(pe[3], 2, 64);
    po2[0] = __shfl_xor(po[0], 2, 64);
    po2[1] = __shfl_xor(po[1], 2, 64);
    po2[2] = __shfl_xor(po[2], 2, 64);
    po2[3] = __shfl_xor(po[3], 2, 64);
    const bool hi = (c0 & 2) != 0;
    const v4f q0 = sel4(hi, pe2, pe);     // h[0..3]
    const v4f q2 = sel4(hi, pe, pe2);     // h[8..11]
    const v4f q1 = sel4(hi, po2, po);     // h[4..7]
    const v4f q3 = sel4(hi, po, po2);     // h[12..15]

    float hh[16];
    #pragma unroll
    for (int i = 0; i < 4; ++i) {
        hh[i]      = q0[i];
        hh[4 + i]  = q1[i];
        hh[8 + i]  = q2[i];
        hh[12 + i] = q3[i];
    }

    // ---- Phase 2: sequential NT stream of up[v] ----
    a0 = (v4f){0.f, 0.f, 0.f, 0.f};
    a1 = a0; a2 = a0; a3 = a0;
    const float* ub = u + (lane << 2);
    #pragma unroll 4
    for (int r = 0; r < RDIM; ++r) {
        const float* ur = ub + (r << 10);
        const v4f u0 = ldnt(ur + 0);
        const v4f u1 = ldnt(ur + 256);
        const v4f u2 = ldnt(ur + 512);
        const v4f u3 = ldnt(ur + 768);
        const float hf = hh[r];
        a0 += hf * u0;
        a1 += hf * u1;
        a2 += hf * u2;
        a3 += hf * u3;
    }
}

// One wave per vocab entry, v-ordered; early-exit if untouched (~13%).
__global__ __launch_bounds__(256) void fused_wave_kernel(
    const int* __restrict__ index_map,
    const float* __restrict__ emb,
    const float* __restrict__ down,
    const float* __restrict__ up,
    const int* __restrict__ head,
    const int* __restrict__ next,
    float* __restrict__ out, int V)
{
    __shared__ v4f els4[4][DDIM / 4];
    const int lane = threadIdx.x & 63;
    const int wib  = threadIdx.x >> 6;
    const int v    = (blockIdx.x << 2) | wib;
    if (v >= V) return;
    const int n0 = head[v];
    if (n0 < 0) return;                       // untouched vocab entry

    // Stage e row (4KB) into this wave's LDS slice (cached loads; emb rows
    // may be shared across v via index_map collisions).
    const v4f* e4 = (const v4f*)(emb + (size_t)index_map[v] * DDIM);
    els4[wib][lane]       = e4[lane];
    els4[wib][lane + 64]  = e4[lane + 64];
    els4[wib][lane + 128] = e4[lane + 128];
    els4[wib][lane + 192] = e4[lane + 192];
    const float* e_lds = (const float*)&els4[wib][0];

    v4f a0, a1, a2, a3;
    compute_row(e_lds,
                down + (size_t)v * (DDIM * RDIM),
                up   + (size_t)v * (RDIM * DDIM),
                lane, a0, a1, a2, a3);

    // Write the row to every output slot referencing v (NT stores).
    int n = n0;
    while (n >= 0) {
        float* o = out + (size_t)n * DDIM + (lane << 2);
        stnt(o + 0,   a0);
        stnt(o + 256, a1);
        stnt(o + 512, a2);
        stnt(o + 768, a3);
        n = next[n];                           // wave-uniform broadcast load
    }
}

// Fallback (tiny ws): one wave per lookup, same math, no dedup.
__global__ __launch_bounds__(256) void rows_direct_kernel(
    const int* __restrict__ indices,
    const int* __restrict__ index_map,
    const float* __restrict__ emb,
    const float* __restrict__ down,
    const float* __restrict__ up,
    float* __restrict__ out, int N)
{
    __shared__ v4f els4[4][DDIM / 4];
    const int lane = threadIdx.x & 63;
    const int wib  = threadIdx.x >> 6;
    const int nn   = (blockIdx.x << 2) | wib;
    if (nn >= N) return;
    const int v = indices[nn];

    const v4f* e4 = (const v4f*)(emb + (size_t)index_map[v] * DDIM);
    els4[wib][lane]       = e4[lane];
    els4[wib][lane + 64]  = e4[lane + 64];
    els4[wib][lane + 128] = e4[lane + 128];
    els4[wib][lane + 192] = e4[lane + 192];
    const float* e_lds = (const float*)&els4[wib][0];

    v4f a0, a1, a2, a3;
    compute_row(e_lds,
                down + (size_t)v * (DDIM * RDIM),
                up   + (size_t)v * (RDIM * DDIM),
                lane, a0, a1, a2, a3);

    float* o = out + (size_t)nn * DDIM + (lane << 2);
    stnt(o + 0,   a0);
    stnt(o + 256, a1);
    stnt(o + 512, a2);
    stnt(o + 768, a3);
}

extern "C" void kernel_launch(void* const* d_in, const int* in_sizes, int n_in,
                              void* d_out, int out_size, void* d_ws, size_t ws_size,
                              hipStream_t stream)
{
    const int*   indices   = (const int*)d_in[0];
    const int*   index_map = (const int*)d_in[1];
    const float* emb       = (const float*)d_in[2];
    const float* down      = (const float*)d_in[3];
    const float* up        = (const float*)d_in[4];
    float*       out       = (float*)d_out;

    const int N = in_sizes[0];
    const int V = in_sizes[1];

    // ws layout: head[V] | next[N]
    const size_t ws_need = (size_t)(V + N) * sizeof(int);

    if (ws_size >= ws_need) {
        int* head = (int*)d_ws;
        int* next = head + V;
        init_head_kernel<<<(V + 255) / 256, 256, 0, stream>>>(head, V);
        link_kernel<<<(N + 255) / 256, 256, 0, stream>>>(indices, head, next, N);
        fused_wave_kernel<<<(V + 3) / 4, 256, 0, stream>>>(index_map, emb, down, up,
                                                           head, next, out, V);
    } else {
        rows_direct_kernel<<<(N + 3) / 4, 256, 0, stream>>>(indices, index_map, emb,
                                                            down, up, out, N);
    }
}

// Round 9
// 194.839 us; speedup vs baseline: 1.0193x; 1.0193x over previous
//
#include <hip/hip_runtime.h>
#include <hip/hip_bf16.h>

// ReparamEmbeddings: V_ORIG=32000, V_NEW=8000, D=1024, R=16, N=16384
// indices: int32 [N], index_map: int32 [V_NEW]
// emb_weight: f32 [V_ORIG, D], down: f32 [V_NEW, D, R], up: f32 [V_NEW, R, D]
// out: f32 [N, 1, D]
//
// Dedup via linked list + first-touch worklist (random order -- decorrelates
// HBM channel access; v-ordered was measurably worse). ONE ITEM PER WAVE
// (no grid-stride): R7's 4096-wave grid-stride over ~6968 items had 70% of
// waves doing 2 items -> ~15% makespan loss from imbalance. head-init via
// hipMemsetAsync (0xFF == -1). Factor streams + output writes nontemporal;
// e row staged in LDS.

#define DDIM 1024
#define RDIM 16

typedef float v4f __attribute__((ext_vector_type(4)));

static __device__ __forceinline__ v4f ldnt(const float* p) {
    return __builtin_nontemporal_load((const v4f*)p);
}
static __device__ __forceinline__ void stnt(float* p, v4f v) {
    __builtin_nontemporal_store(v, (v4f*)p);
}
static __device__ __forceinline__ v4f sel4(bool c, v4f a, v4f b) {
    v4f r;
    r[0] = c ? a[0] : b[0];
    r[1] = c ? a[1] : b[1];
    r[2] = c ? a[2] : b[2];
    r[3] = c ? a[3] : b[3];
    return r;
}

// link: next[i] = old head; first toucher of v appends v to the worklist.
__global__ __launch_bounds__(256) void link_kernel(const int* __restrict__ idx,
                                                   int* __restrict__ head,
                                                   int* __restrict__ next,
                                                   int* __restrict__ work,
                                                   int* __restrict__ nwork, int n) {
    int i = blockIdx.x * 256 + threadIdx.x;
    if (i < n) {
        int v = idx[i];
        int old = atomicExch(&head[v], i);
        next[i] = old;
        if (old < 0) work[atomicAdd(nwork, 1)] = v;
    }
}

// Compute the output row for vocab entry v into a0..a3.
// Phase 1: c0=lane&3 owns r-quad [4c0,4c0+4); dgrp=lane>>2; d = dgrp+16k.
//   down byte addr = lane*16 + k*1024 -> contiguous 1KB per wave instr.
// Butterfly masks 4..32 reduce each lane-class; 12-shuffle ladder
// redistributes all 16 h values to every lane.
// Phase 2: lane owns d = q*256 + lane*4; up rows wave-uniform, coalesced.
static __device__ __forceinline__ void compute_row(
    const float* __restrict__ e_lds,
    const float* __restrict__ dn,
    const float* __restrict__ u,
    int lane, v4f& a0, v4f& a1, v4f& a2, v4f& a3)
{
    const int c0   = lane & 3;
    const int dgrp = lane >> 2;

    // ---- Phase 1: sequential NT stream of down[v] ----
    v4f hp = {0.f, 0.f, 0.f, 0.f};
    const float* dnb = dn + (dgrp << 4) + (c0 << 2);
    #pragma unroll 8
    for (int k = 0; k < 64; ++k) {
        const float ed = e_lds[(k << 4) + dgrp];      // broadcast ds_read
        const v4f dq = ldnt(dnb + (k << 8));
        hp += ed * dq;
    }

    // ---- Reduce within each class (lanes 4 apart) ----
    #pragma unroll
    for (int m = 4; m < 64; m <<= 1) {
        v4f t;
        t[0] = __shfl_xor(hp[0], m, 64);
        t[1] = __shfl_xor(hp[1], m, 64);
        t[2] = __shfl_xor(hp[2], m, 64);
        t[3] = __shfl_xor(hp[3], m, 64);
        hp += t;
    }

    // ---- Redistribute all four class-quads to every lane ----
    v4f t1;
    t1[0] = __shfl_xor(hp[0], 1, 64);
    t1[1] = __shfl_xor(hp[1], 1, 64);
    t1[2] = __shfl_xor(hp[2], 1, 64);
    t1[3] = __shfl_xor(hp[3], 1, 64);
    const bool odd = (c0 & 1) != 0;
    v4f pe = sel4(odd, t1, hp);
    v4f po = sel4(odd, hp, t1);
    v4f pe2, po2;
    pe2[0] = __shfl_xor(pe[0], 2, 64);
    pe2[1] = __shfl_xor(pe[1], 2, 64);
    pe2[2] = __shfl_xor(pe[2], 2, 64);
    pe2[3] = __shfl_xor(pe[3], 2, 64);
    po2[0] = __shfl_xor(po[0], 2, 64);
    po2[1] = __shfl_xor(po[1], 2, 64);
    po2[2] = __shfl_xor(po[2], 2, 64);
    po2[3] = __shfl_xor(po[3], 2, 64);
    const bool hi = (c0 & 2) != 0;
    const v4f q0 = sel4(hi, pe2, pe);     // h[0..3]
    const v4f q2 = sel4(hi, pe, pe2);     // h[8..11]
    const v4f q1 = sel4(hi, po2, po);     // h[4..7]
    const v4f q3 = sel4(hi, po, po2);     // h[12..15]

    float hh[16];
    #pragma unroll
    for (int i = 0; i < 4; ++i) {
        hh[i]      = q0[i];
        hh[4 + i]  = q1[i];
        hh[8 + i]  = q2[i];
        hh[12 + i] = q3[i];
    }

    // ---- Phase 2: sequential NT stream of up[v] ----
    a0 = (v4f){0.f, 0.f, 0.f, 0.f};
    a1 = a0; a2 = a0; a3 = a0;
    const float* ub = u + (lane << 2);
    #pragma unroll 4
    for (int r = 0; r < RDIM; ++r) {
        const float* ur = ub + (r << 10);
        const v4f u0 = ldnt(ur + 0);
        const v4f u1 = ldnt(ur + 256);
        const v4f u2 = ldnt(ur + 512);
        const v4f u3 = ldnt(ur + 768);
        const float hf = hh[r];
        a0 += hf * u0;
        a1 += hf * u1;
        a2 += hf * u2;
        a3 += hf * u3;
    }
}

// ONE worklist item per wave (grid sized for worst case V/4 items; waves with
// wi >= nwork exit immediately). Random first-touch order preserved.
__global__ __launch_bounds__(256) void fused_wave_kernel(
    const int* __restrict__ index_map,
    const float* __restrict__ emb,
    const float* __restrict__ down,
    const float* __restrict__ up,
    const int* __restrict__ head,
    const int* __restrict__ next,
    const int* __restrict__ work,
    const int* __restrict__ nwork,
    float* __restrict__ out)
{
    __shared__ v4f els4[4][DDIM / 4];
    const int lane = threadIdx.x & 63;
    const int wib  = threadIdx.x >> 6;
    const int wi   = (blockIdx.x << 2) | wib;
    if (wi >= *nwork) return;
    const int v = work[wi];

    // Stage e row (4KB) into this wave's LDS slice (cached loads; emb rows
    // may be shared across v via index_map collisions).
    const v4f* e4 = (const v4f*)(emb + (size_t)index_map[v] * DDIM);
    els4[wib][lane]       = e4[lane];
    els4[wib][lane + 64]  = e4[lane + 64];
    els4[wib][lane + 128] = e4[lane + 128];
    els4[wib][lane + 192] = e4[lane + 192];
    const float* e_lds = (const float*)&els4[wib][0];

    v4f a0, a1, a2, a3;
    compute_row(e_lds,
                down + (size_t)v * (DDIM * RDIM),
                up   + (size_t)v * (RDIM * DDIM),
                lane, a0, a1, a2, a3);

    // Write the row to every output slot referencing v (NT stores).
    int n = head[v];
    while (n >= 0) {
        float* o = out + (size_t)n * DDIM + (lane << 2);
        stnt(o + 0,   a0);
        stnt(o + 256, a1);
        stnt(o + 512, a2);
        stnt(o + 768, a3);
        n = next[n];                           // wave-uniform broadcast load
    }
}

// Fallback (tiny ws): one wave per lookup, same math, no dedup.
__global__ __launch_bounds__(256) void rows_direct_kernel(
    const int* __restrict__ indices,
    const int* __restrict__ index_map,
    const float* __restrict__ emb,
    const float* __restrict__ down,
    const float* __restrict__ up,
    float* __restrict__ out, int N)
{
    __shared__ v4f els4[4][DDIM / 4];
    const int lane = threadIdx.x & 63;
    const int wib  = threadIdx.x >> 6;
    const int nn   = (blockIdx.x << 2) | wib;
    if (nn >= N) return;
    const int v = indices[nn];

    const v4f* e4 = (const v4f*)(emb + (size_t)index_map[v] * DDIM);
    els4[wib][lane]       = e4[lane];
    els4[wib][lane + 64]  = e4[lane + 64];
    els4[wib][lane + 128] = e4[lane + 128];
    els4[wib][lane + 192] = e4[lane + 192];
    const float* e_lds = (const float*)&els4[wib][0];

    v4f a0, a1, a2, a3;
    compute_row(e_lds,
                down + (size_t)v * (DDIM * RDIM),
                up   + (size_t)v * (RDIM * DDIM),
                lane, a0, a1, a2, a3);

    float* o = out + (size_t)nn * DDIM + (lane << 2);
    stnt(o + 0,   a0);
    stnt(o + 256, a1);
    stnt(o + 512, a2);
    stnt(o + 768, a3);
}

extern "C" void kernel_launch(void* const* d_in, const int* in_sizes, int n_in,
                              void* d_out, int out_size, void* d_ws, size_t ws_size,
                              hipStream_t stream)
{
    const int*   indices   = (const int*)d_in[0];
    const int*   index_map = (const int*)d_in[1];
    const float* emb       = (const float*)d_in[2];
    const float* down      = (const float*)d_in[3];
    const float* up        = (const float*)d_in[4];
    float*       out       = (float*)d_out;

    const int N = in_sizes[0];
    const int V = in_sizes[1];

    // ws layout: head[V] | next[N] | work[V] | nwork[1]
    const size_t ws_need = (size_t)(2 * V + N + 1) * sizeof(int);

    if (ws_size >= ws_need) {
        int* head  = (int*)d_ws;
        int* next  = head + V;
        int* work  = next + N;
        int* nwork = work + V;
        // head = -1 (0xFF bytes); nwork = 0. Stream-ordered, graph-capture safe.
        hipMemsetAsync(head, 0xFF, (size_t)V * sizeof(int), stream);
        hipMemsetAsync(nwork, 0x00, sizeof(int), stream);
        link_kernel<<<(N + 255) / 256, 256, 0, stream>>>(indices, head, next, work, nwork, N);
        fused_wave_kernel<<<(V + 3) / 4, 256, 0, stream>>>(index_map, emb, down, up,
                                                           head, next, work, nwork, out);
    } else {
        rows_direct_kernel<<<(N + 3) / 4, 256, 0, stream>>>(indices, index_map, emb,
                                                            down, up, out, N);
    }
}

// Round 10
// 185.504 us; speedup vs baseline: 1.0706x; 1.0503x over previous
//
#include <hip/hip_runtime.h>
#include <hip/hip_bf16.h>

// ReparamEmbeddings: V_ORIG=32000, V_NEW=8000, D=1024, R=16, N=16384
// indices: int32 [N], index_map: int32 [V_NEW]
// emb_weight: f32 [V_ORIG, D], down: f32 [V_NEW, D, R], up: f32 [V_NEW, R, D]
// out: f32 [N, 1, D]
//
// Dedup via linked list + first-touch worklist (random order; v-ordered was
// worse -- correlated HBM channel phase). TWO PURE-STREAM KERNELS:
//   A: h[wi] = e^T . down[v]   (one sequential 64KB down-stream per item)
//   B: out   = h . up[v]       (one sequential 64KB up-stream per item)
// This removes the per-item phase drain of the fused kernel (phase-2 loads
// could not issue until the full down-stream + 30-shuffle reduce finished),
// so every resident wave always has loads in flight. Factor streams + out
// writes are nontemporal; h round-trip is ~0.9MB (L3).

#define DDIM 1024
#define RDIM 16

typedef float v4f __attribute__((ext_vector_type(4)));

static __device__ __forceinline__ v4f ldnt(const float* p) {
    return __builtin_nontemporal_load((const v4f*)p);
}
static __device__ __forceinline__ void stnt(float* p, v4f v) {
    __builtin_nontemporal_store(v, (v4f*)p);
}

// link: next[i] = old head; first toucher of v appends v to the worklist.
__global__ __launch_bounds__(256) void link_kernel(const int* __restrict__ idx,
                                                   int* __restrict__ head,
                                                   int* __restrict__ next,
                                                   int* __restrict__ work,
                                                   int* __restrict__ nwork, int n) {
    int i = blockIdx.x * 256 + threadIdx.x;
    if (i < n) {
        int v = idx[i];
        int old = atomicExch(&head[v], i);
        next[i] = old;
        if (old < 0) work[atomicAdd(nwork, 1)] = v;
    }
}

// ---- Kernel A: h[wi*16 + r] = sum_d e[d] * down[v][d][r] ----------------
// Lane layout: c0=lane&3 owns r-quad [4c0,4c0+4); dgrp=lane>>2; d=dgrp+16k.
// down byte addr = lane*16 + k*1024 -> contiguous 1KB per wave instruction.
// Butterfly masks 4..32 reduce each class; lanes 0..3 then hold the four
// class quads -- no redistribute ladder needed.
__global__ __launch_bounds__(256) void h_kernel(
    const int* __restrict__ index_map,
    const float* __restrict__ emb,
    const float* __restrict__ down,
    const int* __restrict__ work,
    const int* __restrict__ nwork,
    float* __restrict__ h)
{
    __shared__ v4f els4[4][DDIM / 4];
    const int lane = threadIdx.x & 63;
    const int wib  = threadIdx.x >> 6;
    const int nw   = *nwork;
    const int stride = gridDim.x << 2;

    for (int wi = (blockIdx.x << 2) + wib; wi < nw; wi += stride) {
        const int v = work[wi];

        // Stage e row (4KB) into this wave's LDS slice (cached loads).
        const v4f* e4 = (const v4f*)(emb + (size_t)index_map[v] * DDIM);
        els4[wib][lane]       = e4[lane];
        els4[wib][lane + 64]  = e4[lane + 64];
        els4[wib][lane + 128] = e4[lane + 128];
        els4[wib][lane + 192] = e4[lane + 192];
        const float* e_lds = (const float*)&els4[wib][0];

        const int c0   = lane & 3;
        const int dgrp = lane >> 2;
        const float* dnb = down + (size_t)v * (DDIM * RDIM) + (dgrp << 4) + (c0 << 2);

        v4f hp = {0.f, 0.f, 0.f, 0.f};
        #pragma unroll 8
        for (int k = 0; k < 64; ++k) {
            const float ed = e_lds[(k << 4) + dgrp];      // broadcast ds_read
            const v4f dq = ldnt(dnb + (k << 8));
            hp += ed * dq;
        }

        #pragma unroll
        for (int m = 4; m < 64; m <<= 1) {
            v4f t;
            t[0] = __shfl_xor(hp[0], m, 64);
            t[1] = __shfl_xor(hp[1], m, 64);
            t[2] = __shfl_xor(hp[2], m, 64);
            t[3] = __shfl_xor(hp[3], m, 64);
            hp += t;
        }

        if (lane < 4)                                      // lane == c0
            *(v4f*)(h + (size_t)wi * RDIM + (lane << 2)) = hp;
    }
}

// ---- Kernel B: out[n] = h[wi] . up[v], for every n in v's chain ---------
// Lane owns d = q*256 + lane*4; up rows wave-uniform, fully coalesced.
__global__ __launch_bounds__(256) void out_kernel(
    const float* __restrict__ up,
    const int* __restrict__ head,
    const int* __restrict__ next,
    const int* __restrict__ work,
    const int* __restrict__ nwork,
    const float* __restrict__ h,
    float* __restrict__ out)
{
    const int lane = threadIdx.x & 63;
    const int wib  = threadIdx.x >> 6;
    const int nw   = *nwork;
    const int stride = gridDim.x << 2;

    for (int wi = (blockIdx.x << 2) + wib; wi < nw; wi += stride) {
        const int v = work[wi];

        // h quads: wave-uniform 64B (L2/L3 hit).
        const v4f* hv = (const v4f*)(h + (size_t)wi * RDIM);
        const v4f h0 = hv[0], h1 = hv[1], h2 = hv[2], h3 = hv[3];
        float hh[16];
        #pragma unroll
        for (int i = 0; i < 4; ++i) {
            hh[i]      = h0[i];
            hh[4 + i]  = h1[i];
            hh[8 + i]  = h2[i];
            hh[12 + i] = h3[i];
        }

        v4f a0 = {0.f, 0.f, 0.f, 0.f}, a1 = a0, a2 = a0, a3 = a0;
        const float* ub = up + (size_t)v * (RDIM * DDIM) + (lane << 2);
        #pragma unroll 4
        for (int r = 0; r < RDIM; ++r) {
            const float* ur = ub + (r << 10);
            const v4f u0 = ldnt(ur + 0);
            const v4f u1 = ldnt(ur + 256);
            const v4f u2 = ldnt(ur + 512);
            const v4f u3 = ldnt(ur + 768);
            const float hf = hh[r];
            a0 += hf * u0;
            a1 += hf * u1;
            a2 += hf * u2;
            a3 += hf * u3;
        }

        int n = head[v];
        while (n >= 0) {
            float* o = out + (size_t)n * DDIM + (lane << 2);
            stnt(o + 0,   a0);
            stnt(o + 256, a1);
            stnt(o + 512, a2);
            stnt(o + 768, a3);
            n = next[n];                       // wave-uniform broadcast load
        }
    }
}

// Fallback (tiny ws): one wave per lookup, fused, no dedup.
static __device__ __forceinline__ v4f sel4(bool c, v4f a, v4f b) {
    v4f r;
    r[0] = c ? a[0] : b[0];
    r[1] = c ? a[1] : b[1];
    r[2] = c ? a[2] : b[2];
    r[3] = c ? a[3] : b[3];
    return r;
}

__global__ __launch_bounds__(256) void rows_direct_kernel(
    const int* __restrict__ indices,
    const int* __restrict__ index_map,
    const float* __restrict__ emb,
    const float* __restrict__ down,
    const float* __restrict__ up,
    float* __restrict__ out, int N)
{
    __shared__ v4f els4[4][DDIM / 4];
    const int lane = threadIdx.x & 63;
    const int wib  = threadIdx.x >> 6;
    const int nn   = (blockIdx.x << 2) | wib;
    if (nn >= N) return;
    const int v = indices[nn];

    const v4f* e4 = (const v4f*)(emb + (size_t)index_map[v] * DDIM);
    els4[wib][lane]       = e4[lane];
    els4[wib][lane + 64]  = e4[lane + 64];
    els4[wib][lane + 128] = e4[lane + 128];
    els4[wib][lane + 192] = e4[lane + 192];
    const float* e_lds = (const float*)&els4[wib][0];

    const int c0   = lane & 3;
    const int dgrp = lane >> 2;
    const float* dnb = down + (size_t)v * (DDIM * RDIM) + (dgrp << 4) + (c0 << 2);

    v4f hp = {0.f, 0.f, 0.f, 0.f};
    #pragma unroll 8
    for (int k = 0; k < 64; ++k) {
        const float ed = e_lds[(k << 4) + dgrp];
        const v4f dq = ldnt(dnb + (k << 8));
        hp += ed * dq;
    }
    #pragma unroll
    for (int m = 4; m < 64; m <<= 1) {
        v4f t;
        t[0] = __shfl_xor(hp[0], m, 64);
        t[1] = __shfl_xor(hp[1], m, 64);
        t[2] = __shfl_xor(hp[2], m, 64);
        t[3] = __shfl_xor(hp[3], m, 64);
        hp += t;
    }
    v4f t1;
    t1[0] = __shfl_xor(hp[0], 1, 64);
    t1[1] = __shfl_xor(hp[1], 1, 64);
    t1[2] = __shfl_xor(hp[2], 1, 64);
    t1[3] = __shfl_xor(hp[3], 1, 64);
    const bool odd = (c0 & 1) != 0;
    v4f pe = sel4(odd, t1, hp);
    v4f po = sel4(odd, hp, t1);
    v4f pe2, po2;
    pe2[0] = __shfl_xor(pe[0], 2, 64);
    pe2[1] = __shfl_xor(pe[1], 2, 64);
    pe2[2] = __shfl_xor(pe[2], 2, 64);
    pe2[3] = __shfl_xor(pe[3], 2, 64);
    po2[0] = __shfl_xor(po[0], 2, 64);
    po2[1] = __shfl_xor(po[1], 2, 64);
    po2[2] = __shfl_xor(po[2], 2, 64);
    po2[3] = __shfl_xor(po[3], 2, 64);
    const bool hi = (c0 & 2) != 0;
    const v4f q0 = sel4(hi, pe2, pe);
    const v4f q2 = sel4(hi, pe, pe2);
    const v4f q1 = sel4(hi, po2, po);
    const v4f q3 = sel4(hi, po, po2);

    float hh[16];
    #pragma unroll
    for (int i = 0; i < 4; ++i) {
        hh[i]      = q0[i];
        hh[4 + i]  = q1[i];
        hh[8 + i]  = q2[i];
        hh[12 + i] = q3[i];
    }

    v4f a0 = {0.f, 0.f, 0.f, 0.f}, a1 = a0, a2 = a0, a3 = a0;
    const float* ub = up + (size_t)v * (RDIM * DDIM) + (lane << 2);
    #pragma unroll 4
    for (int r = 0; r < RDIM; ++r) {
        const float* ur = ub + (r << 10);
        const v4f u0 = ldnt(ur + 0);
        const v4f u1 = ldnt(ur + 256);
        const v4f u2 = ldnt(ur + 512);
        const v4f u3 = ldnt(ur + 768);
        const float hf = hh[r];
        a0 += hf * u0;
        a1 += hf * u1;
        a2 += hf * u2;
        a3 += hf * u3;
    }
    float* o = out + (size_t)nn * DDIM + (lane << 2);
    stnt(o + 0,   a0);
    stnt(o + 256, a1);
    stnt(o + 512, a2);
    stnt(o + 768, a3);
}

extern "C" void kernel_launch(void* const* d_in, const int* in_sizes, int n_in,
                              void* d_out, int out_size, void* d_ws, size_t ws_size,
                              hipStream_t stream)
{
    const int*   indices   = (const int*)d_in[0];
    const int*   index_map = (const int*)d_in[1];
    const float* emb       = (const float*)d_in[2];
    const float* down      = (const float*)d_in[3];
    const float* up        = (const float*)d_in[4];
    float*       out       = (float*)d_out;

    const int N = in_sizes[0];
    const int V = in_sizes[1];

    // ws layout (h first for 16B alignment):
    //   h[V*16] floats | head[V] | next[N] | work[V] | nwork[1]
    const size_t ws_need = (size_t)V * RDIM * sizeof(float)
                         + (size_t)(2 * V + N + 1) * sizeof(int);

    if (ws_size >= ws_need) {
        float* h     = (float*)d_ws;
        int*   head  = (int*)(h + (size_t)V * RDIM);
        int*   next  = head + V;
        int*   work  = next + N;
        int*   nwork = work + V;
        hipMemsetAsync(head, 0xFF, (size_t)V * sizeof(int), stream);
        hipMemsetAsync(nwork, 0x00, sizeof(int), stream);
        link_kernel<<<(N + 255) / 256, 256, 0, stream>>>(indices, head, next, work, nwork, N);
        h_kernel<<<1024, 256, 0, stream>>>(index_map, emb, down, work, nwork, h);
        out_kernel<<<1024, 256, 0, stream>>>(up, head, next, work, nwork, h, out);
    } else {
        rows_direct_kernel<<<(N + 3) / 4, 256, 0, stream>>>(indices, index_map, emb,
                                                            down, up, out, N);
    }
}